// Round 13
// baseline (689.881 us; speedup 1.0000x reference)
//
#include <hip/hip_runtime.h>

typedef _Float16 h2 __attribute__((ext_vector_type(2)));
typedef _Float16 h8 __attribute__((ext_vector_type(8)));
typedef __fp16   g2 __attribute__((ext_vector_type(2)));
typedef __fp16   g8 __attribute__((ext_vector_type(8)));
typedef float    f32x4 __attribute__((ext_vector_type(4)));

#define TT 2048
#define HH 64
#define NL 8
#define NB 256
#define G  16           // timesteps per sync interval
#define NCH (TT/G)      // 128 chunks per layer
#define NI  (NCH + NL)  // 136 intervals

union GU  { g8 v; g2 p[4]; h8 h; };   // LDS <-> MFMA frag bitcast
union FR8 { g8 v; int i[4]; };        // frag from 4 bperm'd b32
union IR  { int i; g2 h2v; };         // packed f16 pair <-> b32

// buf byte layout: boundary l (0..8), phase P (0..1), slot j (0..15), 64 f16.
// Within a slot row (128 B) the 16-B chunk c is stored at index c^(j&7).
#define PH_BASE(l, P) (((l)*2 + (P)) * 2048)
#define CH_OFF(j, c)  ((j)*128 + ((((c) ^ ((j)&7))) * 16))

// preT2: per layer [nn][t][j] f32, nn-stride 68 (17 chunks, odd), t-stride 16.
#define PRE_NN 68
#define PRE_L  (16*PRE_NN)

__device__ __forceinline__ float tanh_fast(float v){
    float e = __expf(2.0f * v);
    float r = __builtin_amdgcn_rcpf(e + 1.0f);
    return fmaf(-2.0f, r, 1.0f);
}

// ---------------------------------------------------------------------------
// R12 flag-sync structure; the serial recurrence is now FULLY IN-REGISTER:
//  - After the h-MFMAs, lane (g,nn) holds y[t*16+nn] for ALL t=0..3 (D cols).
//    tanh all 4 -> pack P0=(h[nn],h[16+nn]), P1=(h[32+nn],h[48+nn]) as b32.
//  - Next step's A-frag via 8 ds_bpermute_b32 (crossbar, no LDS memory):
//    k-map  k = kt*32 + e*16 + g*4 + q  (bijective; B-side precomputed to
//    match, so the HW's internal k order cancels as in R5/R8/R9).
//    src lane = (lane&32) | (g*4+q)  -- works for 64- or 32-half bpermute.
//  - The LDS write->read round-trip (the 647-cyc/step pacer, R12 evidence)
//    is OFF the chain: boundary writes are fire-and-forget for the consumer.
//  - pre (x-proj + bias) readback: all 4 t per lane, staggered b128 quads.
// ---------------------------------------------------------------------------

#define LDQ(d0, d1, d2, d3, qd) { \
    const float* pw = preW + nn*PRE_NN + (qd)*4; \
    d0 = *(const f32x4*)(pw);      d1 = *(const f32x4*)(pw + 16); \
    d2 = *(const f32x4*)(pw + 32); d3 = *(const f32x4*)(pw + 48); \
}

#define INTERVAL(MM, P, XC, XN) { \
    const int mm = (MM); \
    const bool act = (unsigned)(mm - wv) < (unsigned)NCH; \
    if (wv == 0){ \
        if (mm + 1 < NCH){ \
            _Pragma("unroll") \
            for (int j = 0; j < G; ++j) \
                *(_Float16*)(BB + PH_BASE(0, 1-(P)) + j*128 + (((lane>>3)^(j&7))*16) + (lane&7)*2) = (_Float16)XC[j]; \
        } \
        if (mm + 2 < NCH){ \
            _Pragma("unroll") \
            for (int j = 0; j < G; ++j) \
                XN[j] = x[((size_t)b*TT + (size_t)(mm+2)*G + j)*HH + lane]; \
        } \
    } \
    if (wv == 7 && mm >= 8){ \
        GU ha0, ha1; \
        ha0.h = *(const h8*)(BB + PH_BASE(8, P) + CH_OFF(nn, g)); \
        ha1.h = *(const h8*)(BB + PH_BASE(8, P) + CH_OFF(nn, 4+g)); \
        f32x4 ay = {0.f, 0.f, 0.f, 0.f}; \
        ay = __builtin_amdgcn_mfma_f32_16x16x32_f16(ha0.v, woutB[0].v, ay, 0, 0, 0); \
        ay = __builtin_amdgcn_mfma_f32_16x16x32_f16(ha1.v, woutB[1].v, ay, 0, 0, 0); \
        if (nn == 0){ \
            f32x4 st; \
            st[0] = ay[0] + bout; st[1] = ay[1] + bout; \
            st[2] = ay[2] + bout; st[3] = ay[3] + bout; \
            *(f32x4*)(yout + (size_t)b*TT + (size_t)(mm-8)*G + g*4) = st; \
        } \
    } \
    if (act){ \
        if (wv > 0){ \
            while (((volatile int*)prodF)[wv] < mm) __builtin_amdgcn_s_sleep(1); \
            asm volatile("" ::: "memory"); \
        } \
        /* ---- x-projection: D[slot][w-row], bias in C (unchanged) ---- */ \
        GU bx0, bx1; \
        bx0.h = *(const h8*)(BB + PH_BASE(wv, P) + CH_OFF(nn, g)); \
        bx1.h = *(const h8*)(BB + PH_BASE(wv, P) + CH_OFF(nn, 4+g)); \
        f32x4 xd0 = {bs[0],bs[0],bs[0],bs[0]}, xd1 = {bs[1],bs[1],bs[1],bs[1]}; \
        f32x4 xd2 = {bs[2],bs[2],bs[2],bs[2]}, xd3 = {bs[3],bs[3],bs[3],bs[3]}; \
        xd0 = __builtin_amdgcn_mfma_f32_16x16x32_f16(bx0.v, wihA[0][0].v, xd0, 0, 0, 0); \
        xd0 = __builtin_amdgcn_mfma_f32_16x16x32_f16(bx1.v, wihA[0][1].v, xd0, 0, 0, 0); \
        xd1 = __builtin_amdgcn_mfma_f32_16x16x32_f16(bx0.v, wihA[1][0].v, xd1, 0, 0, 0); \
        xd1 = __builtin_amdgcn_mfma_f32_16x16x32_f16(bx1.v, wihA[1][1].v, xd1, 0, 0, 0); \
        xd2 = __builtin_amdgcn_mfma_f32_16x16x32_f16(bx0.v, wihA[2][0].v, xd2, 0, 0, 0); \
        xd2 = __builtin_amdgcn_mfma_f32_16x16x32_f16(bx1.v, wihA[2][1].v, xd2, 0, 0, 0); \
        xd3 = __builtin_amdgcn_mfma_f32_16x16x32_f16(bx0.v, wihA[3][0].v, xd3, 0, 0, 0); \
        xd3 = __builtin_amdgcn_mfma_f32_16x16x32_f16(bx1.v, wihA[3][1].v, xd3, 0, 0, 0); \
        asm volatile("" ::: "memory"); \
        ((volatile int*)consF)[wv] = mm; \
        /* spill pre: lane (g,nn) -> [nn][t][g*4..g*4+3] (slots over r) */ \
        *(f32x4*)(preW + nn*PRE_NN + 0*16 + gq) = xd0; \
        *(f32x4*)(preW + nn*PRE_NN + 1*16 + gq) = xd1; \
        *(f32x4*)(preW + nn*PRE_NN + 2*16 + gq) = xd2; \
        *(f32x4*)(preW + nn*PRE_NN + 3*16 + gq) = xd3; \
        if (wv < 7){ \
            while (((volatile int*)consF)[wv+1] < mm-1) __builtin_amdgcn_s_sleep(1); \
            asm volatile("" ::: "memory"); \
        } \
        f32x4 pA0, pA1, pA2, pA3, pB0, pB1, pB2, pB3; \
        LDQ(pA0, pA1, pA2, pA3, 0) \
        /* ---- 16 serial steps: fully in-register recurrence ---- */ \
        _Pragma("unroll") \
        for (int j = 0; j < G; ++j){ \
            FR8 hf0, hf1; \
            hf0.i[0] = __builtin_amdgcn_ds_bpermute(bpa0, P0i); \
            hf0.i[1] = __builtin_amdgcn_ds_bpermute(bpa1, P0i); \
            hf0.i[2] = __builtin_amdgcn_ds_bpermute(bpa2, P0i); \
            hf0.i[3] = __builtin_amdgcn_ds_bpermute(bpa3, P0i); \
            hf1.i[0] = __builtin_amdgcn_ds_bpermute(bpa0, P1i); \
            hf1.i[1] = __builtin_amdgcn_ds_bpermute(bpa1, P1i); \
            hf1.i[2] = __builtin_amdgcn_ds_bpermute(bpa2, P1i); \
            hf1.i[3] = __builtin_amdgcn_ds_bpermute(bpa3, P1i); \
            const f32x4 zz = {0.f, 0.f, 0.f, 0.f}; \
            f32x4 a00 = __builtin_amdgcn_mfma_f32_16x16x32_f16(hf0.v, whhB2[0][0].v, zz, 0, 0, 0); \
            f32x4 a01 = __builtin_amdgcn_mfma_f32_16x16x32_f16(hf1.v, whhB2[0][1].v, zz, 0, 0, 0); \
            f32x4 a10 = __builtin_amdgcn_mfma_f32_16x16x32_f16(hf0.v, whhB2[1][0].v, zz, 0, 0, 0); \
            f32x4 a11 = __builtin_amdgcn_mfma_f32_16x16x32_f16(hf1.v, whhB2[1][1].v, zz, 0, 0, 0); \
            f32x4 a20 = __builtin_amdgcn_mfma_f32_16x16x32_f16(hf0.v, whhB2[2][0].v, zz, 0, 0, 0); \
            f32x4 a21 = __builtin_amdgcn_mfma_f32_16x16x32_f16(hf1.v, whhB2[2][1].v, zz, 0, 0, 0); \
            f32x4 a30 = __builtin_amdgcn_mfma_f32_16x16x32_f16(hf0.v, whhB2[3][0].v, zz, 0, 0, 0); \
            f32x4 a31 = __builtin_amdgcn_mfma_f32_16x16x32_f16(hf1.v, whhB2[3][1].v, zz, 0, 0, 0); \
            float p0, p1, p2, p3; \
            if (j < 4)      { p0 = pA0[j&3]; p1 = pA1[j&3]; p2 = pA2[j&3]; p3 = pA3[j&3]; } \
            else if (j < 8) { p0 = pB0[j&3]; p1 = pB1[j&3]; p2 = pB2[j&3]; p3 = pB3[j&3]; } \
            else if (j < 12){ p0 = pA0[j&3]; p1 = pA1[j&3]; p2 = pA2[j&3]; p3 = pA3[j&3]; } \
            else            { p0 = pB0[j&3]; p1 = pB1[j&3]; p2 = pB2[j&3]; p3 = pB3[j&3]; } \
            const float th0 = tanh_fast(a00[0] + a01[0] + p0); \
            const float th1 = tanh_fast(a10[0] + a11[0] + p1); \
            const float th2 = tanh_fast(a20[0] + a21[0] + p2); \
            const float th3 = tanh_fast(a30[0] + a31[0] + p3); \
            IR n0, n1; \
            n0.h2v = __builtin_amdgcn_cvt_pkrtz(th0, th1); P0i = n0.i; \
            n1.h2v = __builtin_amdgcn_cvt_pkrtz(th2, th3); P1i = n1.i; \
            const float hsel = (g & 2) ? ((g & 1) ? th3 : th2) : ((g & 1) ? th1 : th0); \
            *(_Float16*)(BB + PH_BASE(wv+1, 1-(P)) + j*128 + (((lane>>3)^(j&7))*16) + (lane&7)*2) = (_Float16)hsel; \
            if (j == 1)  LDQ(pB0, pB1, pB2, pB3, 1) \
            if (j == 5)  LDQ(pA0, pA1, pA2, pA3, 2) \
            if (j == 9)  LDQ(pB0, pB1, pB2, pB3, 3) \
            if (mm - wv == NCH-1 && j == G-1) \
                hout[((size_t)wv*NB + b)*HH + lane] = hsel; \
        } \
        asm volatile("" ::: "memory"); \
        ((volatile int*)prodF)[wv+1] = mm + 1; \
    } \
}

__global__ void __launch_bounds__(512) rnn_kernel(
    const float* __restrict__ x,        // [B,T,64]
    const float* __restrict__ h_state,  // [8,B,64]
    const float* __restrict__ W_ih0,    // [64,64]
    const float* __restrict__ W_ih,     // [7,64,64]
    const float* __restrict__ W_hh,     // [8,64,64]
    const float* __restrict__ b_ih,     // [8,64]
    const float* __restrict__ b_hh,     // [8,64]
    const float* __restrict__ W_out,    // [1,64]
    const float* __restrict__ b_out,    // [1]
    float* __restrict__ out)            // y[256*2048] ++ h_final[8*256*64]
{
    __shared__ __attribute__((aligned(16))) _Float16 buf[(NL+1)*2*G*HH];  // 36 KB
    __shared__ __attribute__((aligned(16))) float preT2[NL*PRE_L];        // 34.8 KB
    __shared__ int prodF[16];
    __shared__ int consF[16];
    char* BB = (char*)buf;
    const int tid  = threadIdx.x;
    const int wv   = tid >> 6;     // wave id == layer id
    const int lane = tid & 63;
    const int g    = lane >> 4;    // MFMA lane group
    const int nn   = lane & 15;    // MFMA row-in-tile / column
    const int gq   = g*4;
    const size_t b = blockIdx.x;
    float* preW = preT2 + wv*PRE_L;

    // bpermute addresses: slot-pair q pulls src lane (lane&32)|(g*4+q)
    const int bpa0 = ((lane & 32) | (gq + 0)) << 2;
    const int bpa1 = ((lane & 32) | (gq + 1)) << 2;
    const int bpa2 = ((lane & 32) | (gq + 2)) << 2;
    const int bpa3 = ((lane & 32) | (gq + 3)) << 2;

    // ---- W_ih A-side (x-proj; original k-map, R5-verified) ----
    GU wihA[4][2];
    const float* Wi = (wv == 0) ? W_ih0 : (W_ih + (size_t)(wv-1)*HH*HH);
    #pragma unroll
    for (int t = 0; t < 4; ++t){
        #pragma unroll
        for (int kt = 0; kt < 2; ++kt){
            const float* pi = Wi + (size_t)(t*16 + nn)*HH + kt*32 + g*8;
            f32x4 i0 = *(const f32x4*)(pi), i1 = *(const f32x4*)(pi + 4);
            wihA[t][kt].p[0] = __builtin_amdgcn_cvt_pkrtz(i0[0], i0[1]);
            wihA[t][kt].p[1] = __builtin_amdgcn_cvt_pkrtz(i0[2], i0[3]);
            wihA[t][kt].p[2] = __builtin_amdgcn_cvt_pkrtz(i1[0], i1[1]);
            wihA[t][kt].p[3] = __builtin_amdgcn_cvt_pkrtz(i1[2], i1[3]);
        }
    }
    // ---- W_hh B-side with the bperm-pair k-map:
    //      slot-pair q of kt = (Whh[t*16+nn][kt*32+g*4+q], Whh[t*16+nn][kt*32+16+g*4+q])
    GU whhB2[4][2];
    const float* Wh = W_hh + (size_t)wv*HH*HH;
    #pragma unroll
    for (int t = 0; t < 4; ++t){
        #pragma unroll
        for (int kt = 0; kt < 2; ++kt){
            const float* ph = Wh + (size_t)(t*16 + nn)*HH + kt*32;
            f32x4 c0 = *(const f32x4*)(ph + gq);        // cols kt*32 + g*4 + q
            f32x4 c1 = *(const f32x4*)(ph + 16 + gq);   // cols kt*32 + 16 + g*4 + q
            whhB2[t][kt].p[0] = __builtin_amdgcn_cvt_pkrtz(c0[0], c1[0]);
            whhB2[t][kt].p[1] = __builtin_amdgcn_cvt_pkrtz(c0[1], c1[1]);
            whhB2[t][kt].p[2] = __builtin_amdgcn_cvt_pkrtz(c0[2], c1[2]);
            whhB2[t][kt].p[3] = __builtin_amdgcn_cvt_pkrtz(c0[3], c1[3]);
        }
    }
    // ---- biases per w-row tile (flow through pre) ----
    float bs[4];
    #pragma unroll
    for (int t = 0; t < 4; ++t)
        bs[t] = b_ih[wv*HH + t*16 + nn] + b_hh[wv*HH + t*16 + nn];
    float bout = b_out[0];

    // ---- wave 7: W_out replicated across columns ----
    GU woutB[2];
    if (wv == 7){
        #pragma unroll
        for (int kt = 0; kt < 2; ++kt)
            #pragma unroll
            for (int q = 0; q < 4; ++q)
                woutB[kt].p[q] = __builtin_amdgcn_cvt_pkrtz(
                    W_out[kt*32 + g*8 + q*2], W_out[kt*32 + g*8 + q*2 + 1]);
    }

    // ---- initial h in registers: P0=(h[nn],h[16+nn]), P1=(h[32+nn],h[48+nn])
    int P0i, P1i;
    {
        const float* hsb = h_state + ((size_t)wv*NB + b)*HH + nn;
        IR u0, u1;
        u0.h2v = __builtin_amdgcn_cvt_pkrtz(hsb[0],  hsb[16]); P0i = u0.i;
        u1.h2v = __builtin_amdgcn_cvt_pkrtz(hsb[32], hsb[48]); P1i = u1.i;
    }

    // ---- zero queues, init flags, stage first x chunk ----
    for (int i = tid; i < (NL+1)*2*G*HH; i += 512) buf[i] = (_Float16)0.f;
    if (tid < 16){
        prodF[tid] = 0;
        consF[tid] = tid - 2;
    }
    __syncthreads();
    float xa[G], xb[G];
    if (wv == 0){
        #pragma unroll
        for (int j = 0; j < G; ++j){
            *(_Float16*)(BB + PH_BASE(0, 1) + j*128 + (((lane>>3)^(j&7))*16) + (lane&7)*2)
                = (_Float16)x[((size_t)b*TT + j)*HH + lane];
            xa[j] = x[((size_t)b*TT + G + j)*HH + lane];
        }
    }
    __syncthreads();

    float* yout = out;                    // [B*T]
    float* hout = out + (size_t)NB*TT;    // [8,B,64]

    for (int m2 = 0; m2 < NI; m2 += 2){
        INTERVAL(m2,     1, xa, xb)
        INTERVAL(m2 + 1, 0, xb, xa)
    }
    // no epilogue: interval NI-1 emits y for the final chunk (all 16 slots)
}

extern "C" void kernel_launch(void* const* d_in, const int* in_sizes, int n_in,
                              void* d_out, int out_size, void* d_ws, size_t ws_size,
                              hipStream_t stream) {
    (void)in_sizes; (void)n_in; (void)d_ws; (void)ws_size; (void)out_size;
    const float* x       = (const float*)d_in[0];
    const float* h_state = (const float*)d_in[1];
    const float* W_ih0   = (const float*)d_in[2];
    const float* W_ih    = (const float*)d_in[3];
    const float* W_hh    = (const float*)d_in[4];
    const float* b_ih    = (const float*)d_in[5];
    const float* b_hh    = (const float*)d_in[6];
    const float* W_out   = (const float*)d_in[7];
    const float* b_out   = (const float*)d_in[8];
    float* out = (float*)d_out;

    rnn_kernel<<<dim3(NB), dim3(512), 0, stream>>>(
        x, h_state, W_ih0, W_ih, W_hh, b_ih, b_hh, W_out, b_out, out);
}

// Round 14
// 688.226 us; speedup vs baseline: 1.0024x; 1.0024x over previous
//
#include <hip/hip_runtime.h>

typedef _Float16 h2 __attribute__((ext_vector_type(2)));
typedef _Float16 h8 __attribute__((ext_vector_type(8)));
typedef __fp16   g2 __attribute__((ext_vector_type(2)));
typedef __fp16   g8 __attribute__((ext_vector_type(8)));
typedef float    f32x4 __attribute__((ext_vector_type(4)));

#define TT 2048
#define HH 64
#define NL 8
#define NB 256
#define G  16           // timesteps per sync interval
#define NCH (TT/G)      // 128 chunks per layer
#define NI  (NCH + NL)  // 136 intervals

union GU  { g8 v; g2 p[4]; h8 h; };   // LDS <-> MFMA frag bitcast
union FR8 { g8 v; int i[4]; };        // frag from 4 bperm'd b32
union IR  { int i; g2 h2v; };         // packed f16 pair <-> b32

// buf byte layout: boundary l (0..8), phase P (0..1), slot j (0..15), 64 f16.
// Within a slot row (128 B) the 16-B chunk c is stored at index c^(j&7).
#define PH_BASE(l, P) (((l)*2 + (P)) * 2048)
#define CH_OFF(j, c)  ((j)*128 + ((((c) ^ ((j)&7))) * 16))

// preT2: per layer [nn][t][j] f32, nn-stride 68 (17 chunks, odd), t-stride 16.
#define PRE_NN 68
#define PRE_L  (16*PRE_NN)

__device__ __forceinline__ float tanh_fast(float v){
    float e = __expf(2.0f * v);
    float r = __builtin_amdgcn_rcpf(e + 1.0f);
    return fmaf(-2.0f, r, 1.0f);
}

// ---------------------------------------------------------------------------
// R13 structure (flag sync + fully in-register recurrence via ds_bpermute),
// ONE change: __launch_bounds__(512, 2).
//   R13 evidence: WRITE_SIZE 2560->24476 KB = scratch spills; the compiler's
//   default occupancy target capped VGPRs at 128 while the unrolled loop
//   needs ~180-230. This kernel runs 1 block/CU (grid 256 = CU count), i.e.
//   2 waves/SIMD -> 256 VGPRs/wave available. launch_bounds(512,2) declares
//   exactly that (k = 2*4/(512/64) = 1 block/CU), lifting the cap.
// Everything else byte-identical to R13 for a clean A/B on the spill theory.
// ---------------------------------------------------------------------------

#define LDQ(d0, d1, d2, d3, qd) { \
    const float* pw = preW + nn*PRE_NN + (qd)*4; \
    d0 = *(const f32x4*)(pw);      d1 = *(const f32x4*)(pw + 16); \
    d2 = *(const f32x4*)(pw + 32); d3 = *(const f32x4*)(pw + 48); \
}

#define INTERVAL(MM, P, XC, XN) { \
    const int mm = (MM); \
    const bool act = (unsigned)(mm - wv) < (unsigned)NCH; \
    if (wv == 0){ \
        if (mm + 1 < NCH){ \
            _Pragma("unroll") \
            for (int j = 0; j < G; ++j) \
                *(_Float16*)(BB + PH_BASE(0, 1-(P)) + j*128 + (((lane>>3)^(j&7))*16) + (lane&7)*2) = (_Float16)XC[j]; \
        } \
        if (mm + 2 < NCH){ \
            _Pragma("unroll") \
            for (int j = 0; j < G; ++j) \
                XN[j] = x[((size_t)b*TT + (size_t)(mm+2)*G + j)*HH + lane]; \
        } \
    } \
    if (wv == 7 && mm >= 8){ \
        GU ha0, ha1; \
        ha0.h = *(const h8*)(BB + PH_BASE(8, P) + CH_OFF(nn, g)); \
        ha1.h = *(const h8*)(BB + PH_BASE(8, P) + CH_OFF(nn, 4+g)); \
        f32x4 ay = {0.f, 0.f, 0.f, 0.f}; \
        ay = __builtin_amdgcn_mfma_f32_16x16x32_f16(ha0.v, woutB[0].v, ay, 0, 0, 0); \
        ay = __builtin_amdgcn_mfma_f32_16x16x32_f16(ha1.v, woutB[1].v, ay, 0, 0, 0); \
        if (nn == 0){ \
            f32x4 st; \
            st[0] = ay[0] + bout; st[1] = ay[1] + bout; \
            st[2] = ay[2] + bout; st[3] = ay[3] + bout; \
            *(f32x4*)(yout + (size_t)b*TT + (size_t)(mm-8)*G + g*4) = st; \
        } \
    } \
    if (act){ \
        if (wv > 0){ \
            while (((volatile int*)prodF)[wv] < mm) __builtin_amdgcn_s_sleep(1); \
            asm volatile("" ::: "memory"); \
        } \
        /* ---- x-projection: D[slot][w-row], bias in C (unchanged) ---- */ \
        GU bx0, bx1; \
        bx0.h = *(const h8*)(BB + PH_BASE(wv, P) + CH_OFF(nn, g)); \
        bx1.h = *(const h8*)(BB + PH_BASE(wv, P) + CH_OFF(nn, 4+g)); \
        f32x4 xd0 = {bs[0],bs[0],bs[0],bs[0]}, xd1 = {bs[1],bs[1],bs[1],bs[1]}; \
        f32x4 xd2 = {bs[2],bs[2],bs[2],bs[2]}, xd3 = {bs[3],bs[3],bs[3],bs[3]}; \
        xd0 = __builtin_amdgcn_mfma_f32_16x16x32_f16(bx0.v, wihA[0][0].v, xd0, 0, 0, 0); \
        xd0 = __builtin_amdgcn_mfma_f32_16x16x32_f16(bx1.v, wihA[0][1].v, xd0, 0, 0, 0); \
        xd1 = __builtin_amdgcn_mfma_f32_16x16x32_f16(bx0.v, wihA[1][0].v, xd1, 0, 0, 0); \
        xd1 = __builtin_amdgcn_mfma_f32_16x16x32_f16(bx1.v, wihA[1][1].v, xd1, 0, 0, 0); \
        xd2 = __builtin_amdgcn_mfma_f32_16x16x32_f16(bx0.v, wihA[2][0].v, xd2, 0, 0, 0); \
        xd2 = __builtin_amdgcn_mfma_f32_16x16x32_f16(bx1.v, wihA[2][1].v, xd2, 0, 0, 0); \
        xd3 = __builtin_amdgcn_mfma_f32_16x16x32_f16(bx0.v, wihA[3][0].v, xd3, 0, 0, 0); \
        xd3 = __builtin_amdgcn_mfma_f32_16x16x32_f16(bx1.v, wihA[3][1].v, xd3, 0, 0, 0); \
        asm volatile("" ::: "memory"); \
        ((volatile int*)consF)[wv] = mm; \
        /* spill pre: lane (g,nn) -> [nn][t][g*4..g*4+3] (slots over r) */ \
        *(f32x4*)(preW + nn*PRE_NN + 0*16 + gq) = xd0; \
        *(f32x4*)(preW + nn*PRE_NN + 1*16 + gq) = xd1; \
        *(f32x4*)(preW + nn*PRE_NN + 2*16 + gq) = xd2; \
        *(f32x4*)(preW + nn*PRE_NN + 3*16 + gq) = xd3; \
        if (wv < 7){ \
            while (((volatile int*)consF)[wv+1] < mm-1) __builtin_amdgcn_s_sleep(1); \
            asm volatile("" ::: "memory"); \
        } \
        f32x4 pA0, pA1, pA2, pA3, pB0, pB1, pB2, pB3; \
        LDQ(pA0, pA1, pA2, pA3, 0) \
        /* ---- 16 serial steps: fully in-register recurrence ---- */ \
        _Pragma("unroll") \
        for (int j = 0; j < G; ++j){ \
            FR8 hf0, hf1; \
            hf0.i[0] = __builtin_amdgcn_ds_bpermute(bpa0, P0i); \
            hf0.i[1] = __builtin_amdgcn_ds_bpermute(bpa1, P0i); \
            hf0.i[2] = __builtin_amdgcn_ds_bpermute(bpa2, P0i); \
            hf0.i[3] = __builtin_amdgcn_ds_bpermute(bpa3, P0i); \
            hf1.i[0] = __builtin_amdgcn_ds_bpermute(bpa0, P1i); \
            hf1.i[1] = __builtin_amdgcn_ds_bpermute(bpa1, P1i); \
            hf1.i[2] = __builtin_amdgcn_ds_bpermute(bpa2, P1i); \
            hf1.i[3] = __builtin_amdgcn_ds_bpermute(bpa3, P1i); \
            const f32x4 zz = {0.f, 0.f, 0.f, 0.f}; \
            f32x4 a00 = __builtin_amdgcn_mfma_f32_16x16x32_f16(hf0.v, whhB2[0][0].v, zz, 0, 0, 0); \
            f32x4 a01 = __builtin_amdgcn_mfma_f32_16x16x32_f16(hf1.v, whhB2[0][1].v, zz, 0, 0, 0); \
            f32x4 a10 = __builtin_amdgcn_mfma_f32_16x16x32_f16(hf0.v, whhB2[1][0].v, zz, 0, 0, 0); \
            f32x4 a11 = __builtin_amdgcn_mfma_f32_16x16x32_f16(hf1.v, whhB2[1][1].v, zz, 0, 0, 0); \
            f32x4 a20 = __builtin_amdgcn_mfma_f32_16x16x32_f16(hf0.v, whhB2[2][0].v, zz, 0, 0, 0); \
            f32x4 a21 = __builtin_amdgcn_mfma_f32_16x16x32_f16(hf1.v, whhB2[2][1].v, zz, 0, 0, 0); \
            f32x4 a30 = __builtin_amdgcn_mfma_f32_16x16x32_f16(hf0.v, whhB2[3][0].v, zz, 0, 0, 0); \
            f32x4 a31 = __builtin_amdgcn_mfma_f32_16x16x32_f16(hf1.v, whhB2[3][1].v, zz, 0, 0, 0); \
            float p0, p1, p2, p3; \
            if (j < 4)      { p0 = pA0[j&3]; p1 = pA1[j&3]; p2 = pA2[j&3]; p3 = pA3[j&3]; } \
            else if (j < 8) { p0 = pB0[j&3]; p1 = pB1[j&3]; p2 = pB2[j&3]; p3 = pB3[j&3]; } \
            else if (j < 12){ p0 = pA0[j&3]; p1 = pA1[j&3]; p2 = pA2[j&3]; p3 = pA3[j&3]; } \
            else            { p0 = pB0[j&3]; p1 = pB1[j&3]; p2 = pB2[j&3]; p3 = pB3[j&3]; } \
            const float th0 = tanh_fast(a00[0] + a01[0] + p0); \
            const float th1 = tanh_fast(a10[0] + a11[0] + p1); \
            const float th2 = tanh_fast(a20[0] + a21[0] + p2); \
            const float th3 = tanh_fast(a30[0] + a31[0] + p3); \
            IR n0, n1; \
            n0.h2v = __builtin_amdgcn_cvt_pkrtz(th0, th1); P0i = n0.i; \
            n1.h2v = __builtin_amdgcn_cvt_pkrtz(th2, th3); P1i = n1.i; \
            const float hsel = (g & 2) ? ((g & 1) ? th3 : th2) : ((g & 1) ? th1 : th0); \
            *(_Float16*)(BB + PH_BASE(wv+1, 1-(P)) + j*128 + (((lane>>3)^(j&7))*16) + (lane&7)*2) = (_Float16)hsel; \
            if (j == 1)  LDQ(pB0, pB1, pB2, pB3, 1) \
            if (j == 5)  LDQ(pA0, pA1, pA2, pA3, 2) \
            if (j == 9)  LDQ(pB0, pB1, pB2, pB3, 3) \
            if (mm - wv == NCH-1 && j == G-1) \
                hout[((size_t)wv*NB + b)*HH + lane] = hsel; \
        } \
        asm volatile("" ::: "memory"); \
        ((volatile int*)prodF)[wv+1] = mm + 1; \
    } \
}

__global__ void __launch_bounds__(512, 2) rnn_kernel(
    const float* __restrict__ x,        // [B,T,64]
    const float* __restrict__ h_state,  // [8,B,64]
    const float* __restrict__ W_ih0,    // [64,64]
    const float* __restrict__ W_ih,     // [7,64,64]
    const float* __restrict__ W_hh,     // [8,64,64]
    const float* __restrict__ b_ih,     // [8,64]
    const float* __restrict__ b_hh,     // [8,64]
    const float* __restrict__ W_out,    // [1,64]
    const float* __restrict__ b_out,    // [1]
    float* __restrict__ out)            // y[256*2048] ++ h_final[8*256*64]
{
    __shared__ __attribute__((aligned(16))) _Float16 buf[(NL+1)*2*G*HH];  // 36 KB
    __shared__ __attribute__((aligned(16))) float preT2[NL*PRE_L];        // 34.8 KB
    __shared__ int prodF[16];
    __shared__ int consF[16];
    char* BB = (char*)buf;
    const int tid  = threadIdx.x;
    const int wv   = tid >> 6;     // wave id == layer id
    const int lane = tid & 63;
    const int g    = lane >> 4;    // MFMA lane group
    const int nn   = lane & 15;    // MFMA row-in-tile / column
    const int gq   = g*4;
    const size_t b = blockIdx.x;
    float* preW = preT2 + wv*PRE_L;

    // bpermute addresses: slot-pair q pulls src lane (lane&32)|(g*4+q)
    const int bpa0 = ((lane & 32) | (gq + 0)) << 2;
    const int bpa1 = ((lane & 32) | (gq + 1)) << 2;
    const int bpa2 = ((lane & 32) | (gq + 2)) << 2;
    const int bpa3 = ((lane & 32) | (gq + 3)) << 2;

    // ---- W_ih A-side (x-proj; original k-map, R5-verified) ----
    GU wihA[4][2];
    const float* Wi = (wv == 0) ? W_ih0 : (W_ih + (size_t)(wv-1)*HH*HH);
    #pragma unroll
    for (int t = 0; t < 4; ++t){
        #pragma unroll
        for (int kt = 0; kt < 2; ++kt){
            const float* pi = Wi + (size_t)(t*16 + nn)*HH + kt*32 + g*8;
            f32x4 i0 = *(const f32x4*)(pi), i1 = *(const f32x4*)(pi + 4);
            wihA[t][kt].p[0] = __builtin_amdgcn_cvt_pkrtz(i0[0], i0[1]);
            wihA[t][kt].p[1] = __builtin_amdgcn_cvt_pkrtz(i0[2], i0[3]);
            wihA[t][kt].p[2] = __builtin_amdgcn_cvt_pkrtz(i1[0], i1[1]);
            wihA[t][kt].p[3] = __builtin_amdgcn_cvt_pkrtz(i1[2], i1[3]);
        }
    }
    // ---- W_hh B-side with the bperm-pair k-map:
    //      slot-pair q of kt = (Whh[t*16+nn][kt*32+g*4+q], Whh[t*16+nn][kt*32+16+g*4+q])
    GU whhB2[4][2];
    const float* Wh = W_hh + (size_t)wv*HH*HH;
    #pragma unroll
    for (int t = 0; t < 4; ++t){
        #pragma unroll
        for (int kt = 0; kt < 2; ++kt){
            const float* ph = Wh + (size_t)(t*16 + nn)*HH + kt*32;
            f32x4 c0 = *(const f32x4*)(ph + gq);        // cols kt*32 + g*4 + q
            f32x4 c1 = *(const f32x4*)(ph + 16 + gq);   // cols kt*32 + 16 + g*4 + q
            whhB2[t][kt].p[0] = __builtin_amdgcn_cvt_pkrtz(c0[0], c1[0]);
            whhB2[t][kt].p[1] = __builtin_amdgcn_cvt_pkrtz(c0[1], c1[1]);
            whhB2[t][kt].p[2] = __builtin_amdgcn_cvt_pkrtz(c0[2], c1[2]);
            whhB2[t][kt].p[3] = __builtin_amdgcn_cvt_pkrtz(c0[3], c1[3]);
        }
    }
    // ---- biases per w-row tile (flow through pre) ----
    float bs[4];
    #pragma unroll
    for (int t = 0; t < 4; ++t)
        bs[t] = b_ih[wv*HH + t*16 + nn] + b_hh[wv*HH + t*16 + nn];
    float bout = b_out[0];

    // ---- wave 7: W_out replicated across columns ----
    GU woutB[2];
    if (wv == 7){
        #pragma unroll
        for (int kt = 0; kt < 2; ++kt)
            #pragma unroll
            for (int q = 0; q < 4; ++q)
                woutB[kt].p[q] = __builtin_amdgcn_cvt_pkrtz(
                    W_out[kt*32 + g*8 + q*2], W_out[kt*32 + g*8 + q*2 + 1]);
    }

    // ---- initial h in registers: P0=(h[nn],h[16+nn]), P1=(h[32+nn],h[48+nn])
    int P0i, P1i;
    {
        const float* hsb = h_state + ((size_t)wv*NB + b)*HH + nn;
        IR u0, u1;
        u0.h2v = __builtin_amdgcn_cvt_pkrtz(hsb[0],  hsb[16]); P0i = u0.i;
        u1.h2v = __builtin_amdgcn_cvt_pkrtz(hsb[32], hsb[48]); P1i = u1.i;
    }

    // ---- zero queues, init flags, stage first x chunk ----
    for (int i = tid; i < (NL+1)*2*G*HH; i += 512) buf[i] = (_Float16)0.f;
    if (tid < 16){
        prodF[tid] = 0;
        consF[tid] = tid - 2;
    }
    __syncthreads();
    float xa[G], xb[G];
    if (wv == 0){
        #pragma unroll
        for (int j = 0; j < G; ++j){
            *(_Float16*)(BB + PH_BASE(0, 1) + j*128 + (((lane>>3)^(j&7))*16) + (lane&7)*2)
                = (_Float16)x[((size_t)b*TT + j)*HH + lane];
            xa[j] = x[((size_t)b*TT + G + j)*HH + lane];
        }
    }
    __syncthreads();

    float* yout = out;                    // [B*T]
    float* hout = out + (size_t)NB*TT;    // [8,B,64]

    for (int m2 = 0; m2 < NI; m2 += 2){
        INTERVAL(m2,     1, xa, xb)
        INTERVAL(m2 + 1, 0, xb, xa)
    }
    // no epilogue: interval NI-1 emits y for the final chunk (all 16 slots)
}

extern "C" void kernel_launch(void* const* d_in, const int* in_sizes, int n_in,
                              void* d_out, int out_size, void* d_ws, size_t ws_size,
                              hipStream_t stream) {
    (void)in_sizes; (void)n_in; (void)d_ws; (void)ws_size; (void)out_size;
    const float* x       = (const float*)d_in[0];
    const float* h_state = (const float*)d_in[1];
    const float* W_ih0   = (const float*)d_in[2];
    const float* W_ih    = (const float*)d_in[3];
    const float* W_hh    = (const float*)d_in[4];
    const float* b_ih    = (const float*)d_in[5];
    const float* b_hh    = (const float*)d_in[6];
    const float* W_out   = (const float*)d_in[7];
    const float* b_out   = (const float*)d_in[8];
    float* out = (float*)d_out;

    rnn_kernel<<<dim3(NB), dim3(512), 0, stream>>>(
        x, h_state, W_ih0, W_ih, W_hh, b_ih, b_hh, W_out, b_out, out);
}

// Round 15
// 686.826 us; speedup vs baseline: 1.0044x; 1.0020x over previous
//
#include <hip/hip_runtime.h>

typedef _Float16 h2 __attribute__((ext_vector_type(2)));
typedef _Float16 h8 __attribute__((ext_vector_type(8)));
typedef __fp16   g2 __attribute__((ext_vector_type(2)));
typedef __fp16   g8 __attribute__((ext_vector_type(8)));
typedef float    f32x4 __attribute__((ext_vector_type(4)));

#define TT 2048
#define HH 64
#define NL 8
#define NB 256
#define G  16           // timesteps per sync interval
#define NCH (TT/G)      // 128 chunks per layer
#define NI  (NCH + NL)  // 136 intervals

union GU  { g8 v; g2 p[4]; h8 h; };   // LDS <-> MFMA frag bitcast
union FR8 { g8 v; int i[4]; };        // frag from 4 bperm'd b32
union IR  { int i; g2 h2v; };         // packed f16 pair <-> b32

// buf byte layout: boundary l (0..8), phase P (0..1), slot j (0..15), 64 f16.
// Within a slot row (128 B) the 16-B chunk c is stored at index c^(j&7).
// (boundary 0 is now unused -- x comes through the f32 xq queue below.)
#define PH_BASE(l, P) (((l)*2 + (P)) * 2048)
#define CH_OFF(j, c)  ((j)*128 + ((((c) ^ ((j)&7))) * 16))

// preT2: per layer [nn][t][j] f32, nn-stride 68 (17 chunks, odd), t-stride 16.
#define PRE_NN 68
#define PRE_L  (16*PRE_NN)

// x queue: [phase][slot j][64 f32 + 4 pad], written by global_load_lds
// (linear lane*4 dest), read by wave 0 only. Row stride 68 f32 = 272 B ->
// (nn,nn+8) 2-way bank aliasing only (free).
#define XQ_ROW 68

__device__ __forceinline__ float tanh_fast(float v){
    float e = __expf(2.0f * v);
    float r = __builtin_amdgcn_rcpf(e + 1.0f);
    return fmaf(-2.0f, r, 1.0f);
}

__device__ __forceinline__ void gload_lds4(const float* g, float* l){
    __builtin_amdgcn_global_load_lds(
        (const __attribute__((address_space(1))) void*)g,
        (__attribute__((address_space(3))) void*)l, 4, 0, 0);
}

// ---------------------------------------------------------------------------
// R13 structure (flag sync + fully in-register recurrence via ds_bpermute).
// R14 evidence: launch_bounds(512,2) was a codegen no-op (VGPR stayed 128,
// WRITE_SIZE stayed 24 MB of scratch spills). Two changes:
//  1. __attribute__((amdgpu_waves_per_eu(2,2))): the direct allocator knob
//     (2 waves/EU -> 256-VGPR cap; we run 1 block/CU = 2 waves/SIMD).
//  2. x staging via global_load_lds into the f32 xq queue: deletes xa/xb
//     (32 VGPRs) and all of wave-0's f16 staging work. Wave 0 reads its
//     x-proj A-frags from xq (4 x b128 + 8 cvt), then issues next chunk.
// Everything else identical to R13.
// ---------------------------------------------------------------------------

#define LDQ(d0, d1, d2, d3, qd) { \
    const float* pw = preW + nn*PRE_NN + (qd)*4; \
    d0 = *(const f32x4*)(pw);      d1 = *(const f32x4*)(pw + 16); \
    d2 = *(const f32x4*)(pw + 32); d3 = *(const f32x4*)(pw + 48); \
}

#define INTERVAL(MM, P) { \
    const int mm = (MM); \
    const bool act = (unsigned)(mm - wv) < (unsigned)NCH; \
    if (wv == 7 && mm >= 8){ \
        GU ha0, ha1; \
        ha0.h = *(const h8*)(BB + PH_BASE(8, P) + CH_OFF(nn, g)); \
        ha1.h = *(const h8*)(BB + PH_BASE(8, P) + CH_OFF(nn, 4+g)); \
        f32x4 ay = {0.f, 0.f, 0.f, 0.f}; \
        ay = __builtin_amdgcn_mfma_f32_16x16x32_f16(ha0.v, woutB[0].v, ay, 0, 0, 0); \
        ay = __builtin_amdgcn_mfma_f32_16x16x32_f16(ha1.v, woutB[1].v, ay, 0, 0, 0); \
        if (nn == 0){ \
            f32x4 st; \
            st[0] = ay[0] + bout; st[1] = ay[1] + bout; \
            st[2] = ay[2] + bout; st[3] = ay[3] + bout; \
            *(f32x4*)(yout + (size_t)b*TT + (size_t)(mm-8)*G + g*4) = st; \
        } \
    } \
    if (act){ \
        if (wv > 0){ \
            while (((volatile int*)prodF)[wv] < mm) __builtin_amdgcn_s_sleep(1); \
            asm volatile("" ::: "memory"); \
        } \
        /* ---- x-projection inputs ---- */ \
        GU bx0, bx1; \
        if (wv == 0){ \
            asm volatile("s_waitcnt vmcnt(0)" ::: "memory");   /* chunk mm resident */ \
            const float* xr = xq + (mm&1)*(G*XQ_ROW) + nn*XQ_ROW; \
            f32x4 q0 = *(const f32x4*)(xr + g*8); \
            f32x4 q1 = *(const f32x4*)(xr + g*8 + 4); \
            f32x4 q2 = *(const f32x4*)(xr + 32 + g*8); \
            f32x4 q3 = *(const f32x4*)(xr + 36 + g*8); \
            bx0.p[0] = __builtin_amdgcn_cvt_pkrtz(q0[0], q0[1]); \
            bx0.p[1] = __builtin_amdgcn_cvt_pkrtz(q0[2], q0[3]); \
            bx0.p[2] = __builtin_amdgcn_cvt_pkrtz(q1[0], q1[1]); \
            bx0.p[3] = __builtin_amdgcn_cvt_pkrtz(q1[2], q1[3]); \
            bx1.p[0] = __builtin_amdgcn_cvt_pkrtz(q2[0], q2[1]); \
            bx1.p[1] = __builtin_amdgcn_cvt_pkrtz(q2[2], q2[3]); \
            bx1.p[2] = __builtin_amdgcn_cvt_pkrtz(q3[0], q3[1]); \
            bx1.p[3] = __builtin_amdgcn_cvt_pkrtz(q3[2], q3[3]); \
            if (mm + 1 < NCH){ \
                const float* gx = x + ((size_t)b*TT + (size_t)(mm+1)*G)*HH + lane; \
                float* lq = xq + (1-(mm&1))*(G*XQ_ROW); \
                _Pragma("unroll") \
                for (int j = 0; j < G; ++j) \
                    gload_lds4(gx + j*HH, lq + j*XQ_ROW); \
            } \
        } else { \
            bx0.h = *(const h8*)(BB + PH_BASE(wv, P) + CH_OFF(nn, g)); \
            bx1.h = *(const h8*)(BB + PH_BASE(wv, P) + CH_OFF(nn, 4+g)); \
        } \
        f32x4 xd0 = {bs[0],bs[0],bs[0],bs[0]}, xd1 = {bs[1],bs[1],bs[1],bs[1]}; \
        f32x4 xd2 = {bs[2],bs[2],bs[2],bs[2]}, xd3 = {bs[3],bs[3],bs[3],bs[3]}; \
        xd0 = __builtin_amdgcn_mfma_f32_16x16x32_f16(bx0.v, wihA[0][0].v, xd0, 0, 0, 0); \
        xd0 = __builtin_amdgcn_mfma_f32_16x16x32_f16(bx1.v, wihA[0][1].v, xd0, 0, 0, 0); \
        xd1 = __builtin_amdgcn_mfma_f32_16x16x32_f16(bx0.v, wihA[1][0].v, xd1, 0, 0, 0); \
        xd1 = __builtin_amdgcn_mfma_f32_16x16x32_f16(bx1.v, wihA[1][1].v, xd1, 0, 0, 0); \
        xd2 = __builtin_amdgcn_mfma_f32_16x16x32_f16(bx0.v, wihA[2][0].v, xd2, 0, 0, 0); \
        xd2 = __builtin_amdgcn_mfma_f32_16x16x32_f16(bx1.v, wihA[2][1].v, xd2, 0, 0, 0); \
        xd3 = __builtin_amdgcn_mfma_f32_16x16x32_f16(bx0.v, wihA[3][0].v, xd3, 0, 0, 0); \
        xd3 = __builtin_amdgcn_mfma_f32_16x16x32_f16(bx1.v, wihA[3][1].v, xd3, 0, 0, 0); \
        asm volatile("" ::: "memory"); \
        ((volatile int*)consF)[wv] = mm; \
        /* spill pre: lane (g,nn) -> [nn][t][g*4..g*4+3] (slots over r) */ \
        *(f32x4*)(preW + nn*PRE_NN + 0*16 + gq) = xd0; \
        *(f32x4*)(preW + nn*PRE_NN + 1*16 + gq) = xd1; \
        *(f32x4*)(preW + nn*PRE_NN + 2*16 + gq) = xd2; \
        *(f32x4*)(preW + nn*PRE_NN + 3*16 + gq) = xd3; \
        if (wv < 7){ \
            while (((volatile int*)consF)[wv+1] < mm-1) __builtin_amdgcn_s_sleep(1); \
            asm volatile("" ::: "memory"); \
        } \
        f32x4 pA0, pA1, pA2, pA3, pB0, pB1, pB2, pB3; \
        LDQ(pA0, pA1, pA2, pA3, 0) \
        /* ---- 16 serial steps: fully in-register recurrence ---- */ \
        _Pragma("unroll") \
        for (int j = 0; j < G; ++j){ \
            FR8 hf0, hf1; \
            hf0.i[0] = __builtin_amdgcn_ds_bpermute(bpa0, P0i); \
            hf0.i[1] = __builtin_amdgcn_ds_bpermute(bpa1, P0i); \
            hf0.i[2] = __builtin_amdgcn_ds_bpermute(bpa2, P0i); \
            hf0.i[3] = __builtin_amdgcn_ds_bpermute(bpa3, P0i); \
            hf1.i[0] = __builtin_amdgcn_ds_bpermute(bpa0, P1i); \
            hf1.i[1] = __builtin_amdgcn_ds_bpermute(bpa1, P1i); \
            hf1.i[2] = __builtin_amdgcn_ds_bpermute(bpa2, P1i); \
            hf1.i[3] = __builtin_amdgcn_ds_bpermute(bpa3, P1i); \
            const f32x4 zz = {0.f, 0.f, 0.f, 0.f}; \
            f32x4 a00 = __builtin_amdgcn_mfma_f32_16x16x32_f16(hf0.v, whhB2[0][0].v, zz, 0, 0, 0); \
            f32x4 a01 = __builtin_amdgcn_mfma_f32_16x16x32_f16(hf1.v, whhB2[0][1].v, zz, 0, 0, 0); \
            f32x4 a10 = __builtin_amdgcn_mfma_f32_16x16x32_f16(hf0.v, whhB2[1][0].v, zz, 0, 0, 0); \
            f32x4 a11 = __builtin_amdgcn_mfma_f32_16x16x32_f16(hf1.v, whhB2[1][1].v, zz, 0, 0, 0); \
            f32x4 a20 = __builtin_amdgcn_mfma_f32_16x16x32_f16(hf0.v, whhB2[2][0].v, zz, 0, 0, 0); \
            f32x4 a21 = __builtin_amdgcn_mfma_f32_16x16x32_f16(hf1.v, whhB2[2][1].v, zz, 0, 0, 0); \
            f32x4 a30 = __builtin_amdgcn_mfma_f32_16x16x32_f16(hf0.v, whhB2[3][0].v, zz, 0, 0, 0); \
            f32x4 a31 = __builtin_amdgcn_mfma_f32_16x16x32_f16(hf1.v, whhB2[3][1].v, zz, 0, 0, 0); \
            float p0, p1, p2, p3; \
            if (j < 4)      { p0 = pA0[j&3]; p1 = pA1[j&3]; p2 = pA2[j&3]; p3 = pA3[j&3]; } \
            else if (j < 8) { p0 = pB0[j&3]; p1 = pB1[j&3]; p2 = pB2[j&3]; p3 = pB3[j&3]; } \
            else if (j < 12){ p0 = pA0[j&3]; p1 = pA1[j&3]; p2 = pA2[j&3]; p3 = pA3[j&3]; } \
            else            { p0 = pB0[j&3]; p1 = pB1[j&3]; p2 = pB2[j&3]; p3 = pB3[j&3]; } \
            const float th0 = tanh_fast(a00[0] + a01[0] + p0); \
            const float th1 = tanh_fast(a10[0] + a11[0] + p1); \
            const float th2 = tanh_fast(a20[0] + a21[0] + p2); \
            const float th3 = tanh_fast(a30[0] + a31[0] + p3); \
            IR n0, n1; \
            n0.h2v = __builtin_amdgcn_cvt_pkrtz(th0, th1); P0i = n0.i; \
            n1.h2v = __builtin_amdgcn_cvt_pkrtz(th2, th3); P1i = n1.i; \
            const float hsel = (g & 2) ? ((g & 1) ? th3 : th2) : ((g & 1) ? th1 : th0); \
            *(_Float16*)(BB + PH_BASE(wv+1, 1-(P)) + j*128 + (((lane>>3)^(j&7))*16) + (lane&7)*2) = (_Float16)hsel; \
            if (j == 1)  LDQ(pB0, pB1, pB2, pB3, 1) \
            if (j == 5)  LDQ(pA0, pA1, pA2, pA3, 2) \
            if (j == 9)  LDQ(pB0, pB1, pB2, pB3, 3) \
            if (mm - wv == NCH-1 && j == G-1) \
                hout[((size_t)wv*NB + b)*HH + lane] = hsel; \
        } \
        asm volatile("" ::: "memory"); \
        ((volatile int*)prodF)[wv+1] = mm + 1; \
    } \
}

__attribute__((amdgpu_waves_per_eu(2, 2)))
__global__ void __launch_bounds__(512) rnn_kernel(
    const float* __restrict__ x,        // [B,T,64]
    const float* __restrict__ h_state,  // [8,B,64]
    const float* __restrict__ W_ih0,    // [64,64]
    const float* __restrict__ W_ih,     // [7,64,64]
    const float* __restrict__ W_hh,     // [8,64,64]
    const float* __restrict__ b_ih,     // [8,64]
    const float* __restrict__ b_hh,     // [8,64]
    const float* __restrict__ W_out,    // [1,64]
    const float* __restrict__ b_out,    // [1]
    float* __restrict__ out)            // y[256*2048] ++ h_final[8*256*64]
{
    __shared__ __attribute__((aligned(16))) _Float16 buf[(NL+1)*2*G*HH];  // 36 KB
    __shared__ __attribute__((aligned(16))) float preT2[NL*PRE_L];        // 34.8 KB
    __shared__ __attribute__((aligned(16))) float xq[2*G*XQ_ROW];         // 8.5 KB
    __shared__ int prodF[16];
    __shared__ int consF[16];
    char* BB = (char*)buf;
    const int tid  = threadIdx.x;
    const int wv   = tid >> 6;     // wave id == layer id
    const int lane = tid & 63;
    const int g    = lane >> 4;    // MFMA lane group
    const int nn   = lane & 15;    // MFMA row-in-tile / column
    const int gq   = g*4;
    const size_t b = blockIdx.x;
    float* preW = preT2 + wv*PRE_L;

    // bpermute addresses: slot-pair q pulls src lane (lane&32)|(g*4+q)
    const int bpa0 = ((lane & 32) | (gq + 0)) << 2;
    const int bpa1 = ((lane & 32) | (gq + 1)) << 2;
    const int bpa2 = ((lane & 32) | (gq + 2)) << 2;
    const int bpa3 = ((lane & 32) | (gq + 3)) << 2;

    // ---- W_ih A-side (x-proj; original k-map, R5-verified) ----
    GU wihA[4][2];
    const float* Wi = (wv == 0) ? W_ih0 : (W_ih + (size_t)(wv-1)*HH*HH);
    #pragma unroll
    for (int t = 0; t < 4; ++t){
        #pragma unroll
        for (int kt = 0; kt < 2; ++kt){
            const float* pi = Wi + (size_t)(t*16 + nn)*HH + kt*32 + g*8;
            f32x4 i0 = *(const f32x4*)(pi), i1 = *(const f32x4*)(pi + 4);
            wihA[t][kt].p[0] = __builtin_amdgcn_cvt_pkrtz(i0[0], i0[1]);
            wihA[t][kt].p[1] = __builtin_amdgcn_cvt_pkrtz(i0[2], i0[3]);
            wihA[t][kt].p[2] = __builtin_amdgcn_cvt_pkrtz(i1[0], i1[1]);
            wihA[t][kt].p[3] = __builtin_amdgcn_cvt_pkrtz(i1[2], i1[3]);
        }
    }
    // ---- W_hh B-side with the bperm-pair k-map:
    //      slot-pair q of kt = (Whh[t*16+nn][kt*32+g*4+q], Whh[t*16+nn][kt*32+16+g*4+q])
    GU whhB2[4][2];
    const float* Wh = W_hh + (size_t)wv*HH*HH;
    #pragma unroll
    for (int t = 0; t < 4; ++t){
        #pragma unroll
        for (int kt = 0; kt < 2; ++kt){
            const float* ph = Wh + (size_t)(t*16 + nn)*HH + kt*32;
            f32x4 c0 = *(const f32x4*)(ph + gq);        // cols kt*32 + g*4 + q
            f32x4 c1 = *(const f32x4*)(ph + 16 + gq);   // cols kt*32 + 16 + g*4 + q
            whhB2[t][kt].p[0] = __builtin_amdgcn_cvt_pkrtz(c0[0], c1[0]);
            whhB2[t][kt].p[1] = __builtin_amdgcn_cvt_pkrtz(c0[1], c1[1]);
            whhB2[t][kt].p[2] = __builtin_amdgcn_cvt_pkrtz(c0[2], c1[2]);
            whhB2[t][kt].p[3] = __builtin_amdgcn_cvt_pkrtz(c0[3], c1[3]);
        }
    }
    // ---- biases per w-row tile (flow through pre) ----
    float bs[4];
    #pragma unroll
    for (int t = 0; t < 4; ++t)
        bs[t] = b_ih[wv*HH + t*16 + nn] + b_hh[wv*HH + t*16 + nn];
    float bout = b_out[0];

    // ---- wave 7: W_out replicated across columns ----
    GU woutB[2];
    if (wv == 7){
        #pragma unroll
        for (int kt = 0; kt < 2; ++kt)
            #pragma unroll
            for (int q = 0; q < 4; ++q)
                woutB[kt].p[q] = __builtin_amdgcn_cvt_pkrtz(
                    W_out[kt*32 + g*8 + q*2], W_out[kt*32 + g*8 + q*2 + 1]);
    }

    // ---- initial h in registers: P0=(h[nn],h[16+nn]), P1=(h[32+nn],h[48+nn])
    int P0i, P1i;
    {
        const float* hsb = h_state + ((size_t)wv*NB + b)*HH + nn;
        IR u0, u1;
        u0.h2v = __builtin_amdgcn_cvt_pkrtz(hsb[0],  hsb[16]); P0i = u0.i;
        u1.h2v = __builtin_amdgcn_cvt_pkrtz(hsb[32], hsb[48]); P1i = u1.i;
    }

    // ---- zero queues, init flags ----
    for (int i = tid; i < (NL+1)*2*G*HH; i += 512) buf[i] = (_Float16)0.f;
    if (tid < 16){
        prodF[tid] = 0;
        consF[tid] = tid - 2;
    }
    __syncthreads();
    // wave 0: preload x chunk 0 into xq phase 0 (read at interval 0)
    if (wv == 0){
        const float* gx = x + (size_t)b*TT*HH + lane;
        #pragma unroll
        for (int j = 0; j < G; ++j)
            gload_lds4(gx + j*HH, xq + j*XQ_ROW);
    }
    __syncthreads();

    float* yout = out;                    // [B*T]
    float* hout = out + (size_t)NB*TT;    // [8,B,64]

    for (int m2 = 0; m2 < NI; m2 += 2){
        INTERVAL(m2,     1)
        INTERVAL(m2 + 1, 0)
    }
    // no epilogue: interval NI-1 emits y for the final chunk (all 16 slots)
}

extern "C" void kernel_launch(void* const* d_in, const int* in_sizes, int n_in,
                              void* d_out, int out_size, void* d_ws, size_t ws_size,
                              hipStream_t stream) {
    (void)in_sizes; (void)n_in; (void)d_ws; (void)ws_size; (void)out_size;
    const float* x       = (const float*)d_in[0];
    const float* h_state = (const float*)d_in[1];
    const float* W_ih0   = (const float*)d_in[2];
    const float* W_ih    = (const float*)d_in[3];
    const float* W_hh    = (const float*)d_in[4];
    const float* b_ih    = (const float*)d_in[5];
    const float* b_hh    = (const float*)d_in[6];
    const float* W_out   = (const float*)d_in[7];
    const float* b_out   = (const float*)d_in[8];
    float* out = (float*)d_out;

    rnn_kernel<<<dim3(NB), dim3(512), 0, stream>>>(
        x, h_state, W_ih0, W_ih, W_hh, b_ih, b_hh, W_out, b_out, out);
}